// Round 1
// baseline (927.572 us; speedup 1.0000x reference)
//
#include <hip/hip_runtime.h>

typedef __attribute__((ext_vector_type(8))) short short8;
typedef __attribute__((ext_vector_type(4))) short short4v;
typedef __attribute__((ext_vector_type(4))) float f32x4;

#define CDIM   512
#define NROWS  81
#define IMG    (NROWS * CDIM)      // 41472 floats per image
#define PA     520                 // sA row pitch in bf16 (512 + 8 pad)
#define PQ     264                 // sQ row pitch in bf16 (256 + 8 pad)

// LDS byte offsets (all 16B-aligned)
#define SA_BYTES   (NROWS * PA * 2)            // 84240
#define SQ_OFFB    84240
#define SQ_BYTES   (NROWS * PQ * 2)            // 42768
#define SPART_OFFB 127008                      // 16 waves * 256 f32 = 16384 B
#define SATTN_OFFB 143392
#define ST2_OFFB   143776
#define SWGT_OFFB  144160
#define SMEM_BYTES 144544

__device__ __forceinline__ unsigned short f2bf(float f) {
    unsigned int u = __float_as_uint(f);
    u += 0x7fffu + ((u >> 16) & 1u);   // round-to-nearest-even
    return (unsigned short)(u >> 16);
}
__device__ __forceinline__ float bf2f(unsigned short s) {
    return __uint_as_float(((unsigned int)s) << 16);
}

// ---------------- pre-kernel: W fp32 -> bf16, once per launch ----------------
// 256*512 = 131072 elems; 64 blocks * 256 threads * 8 elems
extern "C" __global__ void wconv_kernel(const float* __restrict__ Wfc,
                                        unsigned short* __restrict__ Wbf)
{
    const long i = (long)blockIdx.x * 256 + threadIdx.x;
    const float* src = Wfc + i * 8;
    f32x4 v0 = *(const f32x4*)src;
    f32x4 v1 = *(const f32x4*)(src + 4);
    short8 pk;
    pk[0] = (short)f2bf(v0[0]); pk[1] = (short)f2bf(v0[1]);
    pk[2] = (short)f2bf(v0[2]); pk[3] = (short)f2bf(v0[3]);
    pk[4] = (short)f2bf(v1[0]); pk[5] = (short)f2bf(v1[1]);
    pk[6] = (short)f2bf(v1[2]); pk[7] = (short)f2bf(v1[3]);
    *(short8*)(Wbf + i * 8) = pk;
}

// ---------------- main kernel: 1024 threads (16 waves), 1 image/block -------
extern "C" __global__ void __launch_bounds__(1024, 4)
attn_kernel(const float* __restrict__ x, const unsigned short* __restrict__ Wbf,
            const float* __restrict__ bfc, float* __restrict__ out)
{
    extern __shared__ char smem[];
    unsigned short* sA    = (unsigned short*)(smem);
    unsigned short* sQ    = (unsigned short*)(smem + SQ_OFFB);
    float*          sPart = (float*)(smem + SPART_OFFB);
    float*          sAttn = (float*)(smem + SATTN_OFFB);
    float*          sT2   = (float*)(smem + ST2_OFFB);
    float*          sWgt  = (float*)(smem + SWGT_OFFB);

    const int tid  = threadIdx.x;
    const int wave = tid >> 6;         // 0..15
    const int lane = tid & 63;
    const int r15  = lane & 15;
    const int q    = lane >> 4;
    const long img = blockIdx.x;
    const float* xin = x + img * (long)IMG;

    // ---------- Phase 1: stage x -> sA as bf16, rows indexed by np = n*9+p ----
    // 81 rows over 16 waves: loads hoisted so they pipeline
    {
        f32x4 v0[6], v1[6];
        #pragma unroll
        for (int it = 0; it < 6; ++it) {
            int row = it * 16 + wave;
            if (row < NROWS) {
                int n = row / 9, p = row % 9;
                int h  = (n / 3) * 3 + p / 3;
                int w2 = (n % 3) * 3 + p % 3;
                const float* src = xin + (h * 9 + w2) * CDIM + lane * 8;
                v0[it] = *(const f32x4*)src;
                v1[it] = *(const f32x4*)(src + 4);
            }
        }
        #pragma unroll
        for (int it = 0; it < 6; ++it) {
            int row = it * 16 + wave;
            if (row < NROWS) {
                short8 pk;
                pk[0] = (short)f2bf(v0[it][0]); pk[1] = (short)f2bf(v0[it][1]);
                pk[2] = (short)f2bf(v0[it][2]); pk[3] = (short)f2bf(v0[it][3]);
                pk[4] = (short)f2bf(v1[it][0]); pk[5] = (short)f2bf(v1[it][1]);
                pk[6] = (short)f2bf(v1[it][2]); pk[7] = (short)f2bf(v1[it][3]);
                *(short8*)&sA[row * PA + lane * 8] = pk;
            }
        }
    }
    __syncthreads();

    // ---------- Phase 2: xq = x_fc @ W^T + b  (M=81->96, N=256, K=512) --------
    // 16 waves = 2 M-halves (48 rows) x 8 col-groups (32 cols); W is bf16 now.
    {
        const int wm = wave >> 3;      // 0..1
        const int wn = wave & 7;       // 0..7
        f32x4 acc[3][2];
        #pragma unroll
        for (int i = 0; i < 3; ++i) {
            acc[i][0] = (f32x4){0.f, 0.f, 0.f, 0.f};
            acc[i][1] = (f32x4){0.f, 0.f, 0.f, 0.f};
        }
        const float bias0 = bfc[wn * 32 + r15];
        const float bias1 = bfc[wn * 32 + 16 + r15];
        const unsigned short* wr0 = Wbf + (long)(wn * 32 + r15) * CDIM + q * 8;
        const unsigned short* wr1 = wr0 + 16 * CDIM;

        #pragma unroll 4
        for (int ks = 0; ks < 16; ++ks) {
            short8 b0 = *(const short8*)(wr0 + ks * 32);
            short8 b1 = *(const short8*)(wr1 + ks * 32);
            #pragma unroll
            for (int i = 0; i < 3; ++i) {
                int rowA = (wm * 3 + i) * 16 + r15;
                if (rowA > 80) rowA = 80;                 // tail: harmless dup
                short8 a = *(short8*)&sA[rowA * PA + ks * 32 + q * 8];
                acc[i][0] = __builtin_amdgcn_mfma_f32_16x16x32_bf16(a, b0, acc[i][0], 0, 0, 0);
                acc[i][1] = __builtin_amdgcn_mfma_f32_16x16x32_bf16(a, b1, acc[i][1], 0, 0, 0);
            }
        }
        // epilogue: + bias -> sQ bf16. C/D layout: col=lane&15, row=q*4+reg
        #pragma unroll
        for (int i = 0; i < 3; ++i) {
            int mt = wm * 3 + i;
            #pragma unroll
            for (int nt = 0; nt < 2; ++nt) {
                int col = wn * 32 + nt * 16 + r15;
                float bb = nt ? bias1 : bias0;
                #pragma unroll
                for (int r = 0; r < 4; ++r) {
                    int row = mt * 16 + q * 4 + r;
                    if (row < NROWS)
                        sQ[row * PQ + col] = f2bf(acc[i][nt][r] + bb);
                }
            }
        }
    }
    __syncthreads();

    // ---------- Phase 3: attn partials = sum_p Q_p Q_p^T via mfma(a,a) --------
    // 18 tasks = (p 0..8) x (k-half 0..1) over 16 waves
    {
        f32x4 qacc = (f32x4){0.f, 0.f, 0.f, 0.f};
        for (int t = wave; t < 18; t += 16) {
            int p = t >> 1, kh = t & 1;
            int rq = r15 * 9 + p;
            if (rq > 80) rq = 80;                         // cols m>=9 ignored
            const unsigned short* qrow = &sQ[rq * PQ + kh * 128 + q * 8];
            #pragma unroll
            for (int ks = 0; ks < 4; ++ks) {
                short8 f = *(short8*)&qrow[ks * 32];
                qacc = __builtin_amdgcn_mfma_f32_16x16x32_bf16(f, f, qacc, 0, 0, 0);
            }
        }
        float* pp = &sPart[wave * 256];
        #pragma unroll
        for (int r = 0; r < 4; ++r)
            pp[(q * 4 + r) * 16 + r15] = qacc[r];
    }
    __syncthreads();

    // ---------- Phase 4: softmax chain (fp32, tiny) ---------------------------
    if (tid < 81) {
        int n = tid / 9, m = tid % 9;
        float s = 0.f;
        #pragma unroll
        for (int w = 0; w < 16; ++w) s += sPart[w * 256 + n * 16 + m];
        s *= (1.0f / 48.0f);                              // (hidden*P)^-0.5
        if (n == m) s -= 100.0f;                          // diagonal mask
        sAttn[tid] = s;
    }
    __syncthreads();
    if (tid < 81) {
        int n = tid / 9, k = tid % 9;
        float s = 0.f;
        #pragma unroll
        for (int m = 0; m < 9; ++m) s += sAttn[n * 9 + m] * sAttn[k * 9 + m];
        sT2[tid] = s * (1.0f / 3.0f);                     // N^-0.5
    }
    __syncthreads();
    if (tid < 9) {
        int n = tid;
        float t[9], mx = -1e30f;
        #pragma unroll
        for (int m = 0; m < 9; ++m) { t[m] = sT2[n * 9 + m]; mx = fmaxf(mx, t[m]); }
        float sum = 0.f;
        #pragma unroll
        for (int m = 0; m < 9; ++m) { t[m] = __expf(t[m] - mx); sum += t[m]; }
        float inv = 1.0f / sum;
        float g[9], mx2 = -1e30f;
        #pragma unroll
        for (int m = 0; m < 9; ++m) { g[m] = sAttn[n * 9 + m] + t[m] * inv; mx2 = fmaxf(mx2, g[m]); }
        float sum2 = 0.f;
        #pragma unroll
        for (int m = 0; m < 9; ++m) { g[m] = __expf(g[m] - mx2); sum2 += g[m]; }
        float inv2 = 1.0f / sum2;
        #pragma unroll
        for (int m = 0; m < 9; ++m) sWgt[n * 9 + m] = g[m] * inv2;
    }
    __syncthreads();

    // ---------- Phase 5: out = attn @ V, per-(p, ch-half) waves ---------------
    // Each V row loaded+converted ONCE, applied to all 9 output rows.
    // Accumulation order over m identical to before -> bit-identical output.
    for (int t = wave; t < 18; t += 16) {
        int p = t >> 1, hf = t & 1;
        int c0 = hf * 256 + lane * 4;
        f32x4 av[9];
        #pragma unroll
        for (int n = 0; n < 9; ++n) av[n] = (f32x4){0.f, 0.f, 0.f, 0.f};
        #pragma unroll
        for (int m = 0; m < 9; ++m) {
            short4v v = *(const short4v*)&sA[(m * 9 + p) * PA + c0];
            float vf0 = bf2f((unsigned short)v[0]);
            float vf1 = bf2f((unsigned short)v[1]);
            float vf2 = bf2f((unsigned short)v[2]);
            float vf3 = bf2f((unsigned short)v[3]);
            #pragma unroll
            for (int n = 0; n < 9; ++n) {
                float wt = sWgt[n * 9 + m];               // broadcast LDS read
                av[n][0] += wt * vf0; av[n][1] += wt * vf1;
                av[n][2] += wt * vf2; av[n][3] += wt * vf3;
            }
        }
        #pragma unroll
        for (int n = 0; n < 9; ++n) {
            int h  = (n / 3) * 3 + p / 3;
            int w2 = (n % 3) * 3 + p % 3;
            float* dst = out + img * (long)IMG + (h * 9 + w2) * CDIM + c0;
            *(f32x4*)dst = av[n];
        }
    }
}

extern "C" void kernel_launch(void* const* d_in, const int* in_sizes, int n_in,
                              void* d_out, int out_size, void* d_ws, size_t ws_size,
                              hipStream_t stream) {
    (void)in_sizes; (void)n_in; (void)ws_size; (void)out_size;
    const float* x   = (const float*)d_in[0];
    const float* Wfc = (const float*)d_in[1];
    const float* bfc = (const float*)d_in[2];
    float* o = (float*)d_out;
    unsigned short* Wbf = (unsigned short*)d_ws;   // needs 256 KiB workspace
    hipFuncSetAttribute((const void*)attn_kernel,
                        hipFuncAttributeMaxDynamicSharedMemorySize, SMEM_BYTES);
    wconv_kernel<<<dim3(64), dim3(256), 0, stream>>>(Wfc, Wbf);
    attn_kernel<<<dim3(2048), dim3(1024), SMEM_BYTES, stream>>>(x, Wbf, bfc, o);
}